// Round 17
// baseline (7709.654 us; speedup 1.0000x reference)
//
#include <hip/hip_runtime.h>
#include <hip/hip_bf16.h>

#define BB 2
#define NN 512
#define LL 8192
#define CC 256
#define HH 8
#define DD 32
#define SCALE 0.17677669529663687f
#define WSCALE 1.0f   // faithful world (single change vs r16's 50.0)

typedef unsigned int u32;

__global__ void sentinel(float* out, float val) {
    if (threadIdx.x == 0) out[0] = val;
}

// ---------------------------------------------------------------------------
// f32 GEMM: C = wscale*(A @ W^T) (+bias)(+res)(+gelu). Thread/output.
// ---------------------------------------------------------------------------
template <int RES, int ACT, bool HAS_BIAS>
__global__ __launch_bounds__(256) void sgemm(
    const float* __restrict__ A, const float* __restrict__ W,
    const float* __restrict__ bias, const float* __restrict__ res,
    float* __restrict__ C, int M, int N, int K, float wscale)
{
    int idx = blockIdx.x * 256 + threadIdx.x;
    if (idx >= M * N) return;
    int row = idx / N, col = idx - row * N;
    const float4* a4 = (const float4*)(A + (size_t)row * K);
    const float4* w4 = (const float4*)(W + (size_t)col * K);
    float acc = 0.f;
    int k4 = K >> 2;
    for (int k = 0; k < k4; ++k) {
        float4 a = a4[k], w = w4[k];
        acc += a.x * w.x + a.y * w.y + a.z * w.z + a.w * w.w;
    }
    acc *= wscale;
    if (HAS_BIAS) acc += bias[col];
    if (RES) acc += res[(size_t)row * N + col];
    if (ACT) acc = 0.5f * acc * (1.f + erff(acc * 0.70710678118f));
    C[(size_t)row * N + col] = acc;
}

// ---------------------------------------------------------------------------
// f32 scalar attention (proven kernel, unchanged).
// ---------------------------------------------------------------------------
__global__ __launch_bounds__(256) void attn_f32(
    const float* __restrict__ qp, const float* __restrict__ kp,
    const float* __restrict__ vp, float* __restrict__ op,
    int Lk, int qStride, int kStride, int Nq)
{
    __shared__ float cm[32][8], cs[32][8];
    __shared__ float co[32][8][32];
    int t = threadIdx.x, qi = t >> 3, g = t & 7;
    int b = blockIdx.z, h = blockIdx.y, n0 = blockIdx.x * 32;
    const float4* q4 = (const float4*)(qp + (size_t)(b * Nq + n0 + qi) * qStride + h * DD);
    float q[32];
#pragma unroll
    for (int j = 0; j < 8; ++j) {
        float4 v = q4[j];
        q[4 * j] = v.x; q[4 * j + 1] = v.y; q[4 * j + 2] = v.z; q[4 * j + 3] = v.w;
    }
    float m = -1e30f, s = 0.f, o[32];
#pragma unroll
    for (int d = 0; d < 32; ++d) o[d] = 0.f;
    const float* kb = kp + (size_t)b * Lk * kStride + h * DD;
    const float* vb = vp + (size_t)b * Lk * kStride + h * DD;
    for (int l = g; l < Lk; l += 8) {
        const float4* k4 = (const float4*)(kb + (size_t)l * kStride);
        float dot = 0.f;
#pragma unroll
        for (int j = 0; j < 8; ++j) {
            float4 kv = k4[j];
            dot += q[4 * j] * kv.x + q[4 * j + 1] * kv.y + q[4 * j + 2] * kv.z + q[4 * j + 3] * kv.w;
        }
        dot *= SCALE;
        float mn = fmaxf(m, dot);
        float alpha = __expf(m - mn);
        float p = __expf(dot - mn);
        s = s * alpha + p;
        const float4* v4 = (const float4*)(vb + (size_t)l * kStride);
#pragma unroll
        for (int j = 0; j < 8; ++j) {
            float4 vv = v4[j];
            o[4 * j]     = o[4 * j]     * alpha + p * vv.x;
            o[4 * j + 1] = o[4 * j + 1] * alpha + p * vv.y;
            o[4 * j + 2] = o[4 * j + 2] * alpha + p * vv.z;
            o[4 * j + 3] = o[4 * j + 3] * alpha + p * vv.w;
        }
        m = mn;
    }
    cm[qi][g] = m; cs[qi][g] = s;
#pragma unroll
    for (int d = 0; d < 32; ++d) co[qi][g][d] = o[d];
    __syncthreads();
    for (int idx = t; idx < 1024; idx += 256) {
        int q2 = idx >> 5, d = idx & 31;
        float mm = -1e30f;
#pragma unroll
        for (int w = 0; w < 8; ++w) mm = fmaxf(mm, cm[q2][w]);
        float num = 0.f, den = 0.f;
#pragma unroll
        for (int w = 0; w < 8; ++w) {
            float e = __expf(cm[q2][w] - mm);
            num += e * co[q2][w][d];
            den += e * cs[q2][w];
        }
        op[(size_t)(b * Nq + n0 + q2) * CC + h * DD + d] = num / den;
    }
}

// ---------------------------------------------------------------------------
// f32 mask, faithful weights, f32 store.
// ---------------------------------------------------------------------------
__global__ __launch_bounds__(256) void smask_f32(
    const float* __restrict__ qc, const float* __restrict__ kc,
    const float* __restrict__ w1, const float* __restrict__ b1,
    const float* __restrict__ w2, const float* __restrict__ b2,
    float* __restrict__ mout)
{
    __shared__ float qs[256];
    int n = blockIdx.y, l0 = blockIdx.x * 256;
    qs[threadIdx.x] = qc[(size_t)n * CC + threadIdx.x];
    __syncthreads();
    int l = l0 + threadIdx.x;
    const float* krow = kc + (size_t)l * CC;
    float s[8];
#pragma unroll
    for (int h = 0; h < 8; ++h) {
        float d = 0.f;
#pragma unroll
        for (int dd = 0; dd < 32; ++dd) d += qs[h * 32 + dd] * krow[h * 32 + dd];
        s[h] = d * SCALE;
    }
    float acc2 = b2[0];
#pragma unroll
    for (int o = 0; o < 8; ++o) {
        float f = b1[o];
#pragma unroll
        for (int i = 0; i < 8; ++i) f += s[i] * (w1[o * 8 + i] * WSCALE);
        f = fmaxf(f, 0.f);
        acc2 += f * (w2[o] * WSCALE);
    }
    mout[(size_t)n * LL + l] = fmaxf(acc2, 0.f);
}

// ---------------------------------------------------------------------------
// f32 LayerNorm over C=256, one wave per row, f32 out.
// ---------------------------------------------------------------------------
__global__ __launch_bounds__(256) void ln_f32(
    const float* __restrict__ a, const float* __restrict__ g,
    const float* __restrict__ be, float* __restrict__ out)
{
    int lane = threadIdx.x & 63, wave = threadIdx.x >> 6;
    int row = blockIdx.x * 4 + wave;
    float4 v = *(const float4*)(a + (size_t)row * CC + lane * 4);
    float sum = v.x + v.y + v.z + v.w;
    float sq = v.x * v.x + v.y * v.y + v.z * v.z + v.w * v.w;
#pragma unroll
    for (int mk = 1; mk < 64; mk <<= 1) {
        sum += __shfl_xor(sum, mk);
        sq += __shfl_xor(sq, mk);
    }
    float mean = sum * (1.f / 256.f);
    float var = sq * (1.f / 256.f) - mean * mean;
    float rstd = rsqrtf(var + 1e-5f);
    int c = lane * 4;
    float4 ov;
    ov.x = (v.x - mean) * rstd * g[c + 0] + be[c + 0];
    ov.y = (v.y - mean) * rstd * g[c + 1] + be[c + 1];
    ov.z = (v.z - mean) * rstd * g[c + 2] + be[c + 2];
    ov.w = (v.w - mean) * rstd * g[c + 3] + be[c + 3];
    *(float4*)(out + (size_t)row * CC + c) = ov;
}

// ---------------------------------------------------------------------------
extern "C" void kernel_launch(void* const* d_in, const int* in_sizes, int n_in,
                              void* d_out, int out_size, void* d_ws, size_t ws_size,
                              hipStream_t stream)
{
    (void)in_sizes; (void)n_in; (void)out_size;
    float* outx = (float*)d_out;                 // x: f32, 262144 elems
    float* outm = outx + (size_t)BB * NN * CC;   // mask: f32, 8388608 elems

    const float* query     = (const float*)d_in[0];
    const float* key       = (const float*)d_in[1];
    const float* value     = (const float*)d_in[2];
    const float* sa_qkv_w  = (const float*)d_in[3];
    const float* sa_proj_w = (const float*)d_in[4];
    const float* sa_proj_b = (const float*)d_in[5];
    const float* norm3_g   = (const float*)d_in[6];
    const float* norm3_b   = (const float*)d_in[7];
    const float* q_w       = (const float*)d_in[8];
    const float* k_w       = (const float*)d_in[9];
    const float* v_w       = (const float*)d_in[10];
    const float* ca_proj_w = (const float*)d_in[11];
    const float* ca_proj_b = (const float*)d_in[12];
    const float* l1_w      = (const float*)d_in[13];
    const float* l1_b      = (const float*)d_in[14];
    const float* l2_w      = (const float*)d_in[15];
    const float* l2_b      = (const float*)d_in[16];
    const float* ln1_g     = (const float*)d_in[17];
    const float* ln1_b     = (const float*)d_in[18];
    const float* ln2_g     = (const float*)d_in[19];
    const float* ln2_b     = (const float*)d_in[20];
    const float* fc1_w     = (const float*)d_in[21];
    const float* fc1_b     = (const float*)d_in[22];
    const float* fc2_w     = (const float*)d_in[23];
    const float* fc2_b     = (const float*)d_in[24];

    char* w0 = (char*)d_ws;
    float* unionA = (float*)w0;        w0 += (size_t)16 * 1024 * 1024;
    float* saH = (float*)w0;           w0 += (size_t)1024 * 256 * 4;
    float* x1  = (float*)w0;           w0 += (size_t)1024 * 256 * 4;
    float* x2  = (float*)w0;           w0 += (size_t)1024 * 256 * 4;
    float* tmp = (float*)w0;           w0 += (size_t)1024 * 256 * 4;
    float* qc  = (float*)w0;           w0 += (size_t)1024 * 256 * 4;
    float* caH = (float*)w0;           w0 += (size_t)1024 * 256 * 4;
    size_t need = (size_t)(w0 - (char*)d_ws);
    float* qkv = unionA;
    float* kcb = unionA;
    float* vcb = unionA + (size_t)8192 * 256;
    float* hb  = unionA;

    if (ws_size < need) {
        sentinel<<<dim3(1), dim3(64), 0, stream>>>(outx, 1000.f + (float)(ws_size >> 20));
        return;
    }

    dim3 blk(256);

    // faithful-world pipeline (WSCALE = 1)
    sgemm<0, 0, false><<<dim3(3072), blk, 0, stream>>>(query, sa_qkv_w, nullptr, nullptr, qkv, 1024, 768, 256, WSCALE);
    attn_f32<<<dim3(16, 8, 2), blk, 0, stream>>>(qkv, qkv + 256, qkv + 512, saH, 512, 768, 768, 512);
    sgemm<1, 0, true><<<dim3(1024), blk, 0, stream>>>(saH, sa_proj_w, sa_proj_b, query, tmp, 1024, 256, 256, WSCALE);
    ln_f32<<<dim3(256), blk, 0, stream>>>(tmp, norm3_g, norm3_b, x1);
    sgemm<0, 0, false><<<dim3(1024), blk, 0, stream>>>(x1, q_w, nullptr, nullptr, qc, 1024, 256, 256, WSCALE);
    for (int b = 0; b < 2; ++b) {
        const float* keyb = key + (size_t)b * 8192 * 256;
        const float* valb = value + (size_t)b * 8192 * 256;
        sgemm<0, 0, false><<<dim3(8192), blk, 0, stream>>>(keyb, k_w, nullptr, nullptr, kcb, 8192, 256, 256, WSCALE);
        sgemm<0, 0, false><<<dim3(8192), blk, 0, stream>>>(valb, v_w, nullptr, nullptr, vcb, 8192, 256, 256, WSCALE);
        attn_f32<<<dim3(16, 8, 1), blk, 0, stream>>>(qc + (size_t)b * 512 * 256, kcb, vcb,
                                                     caH + (size_t)b * 512 * 256, 8192, 256, 256, 512);
        smask_f32<<<dim3(32, 512, 1), blk, 0, stream>>>(qc + (size_t)b * 512 * 256, kcb,
                                                        l1_w, l1_b, l2_w, l2_b,
                                                        outm + (size_t)b * 512 * 8192);
    }
    sgemm<1, 0, true><<<dim3(1024), blk, 0, stream>>>(caH, ca_proj_w, ca_proj_b, x1, tmp, 1024, 256, 256, WSCALE);
    ln_f32<<<dim3(256), blk, 0, stream>>>(tmp, ln1_g, ln1_b, x2);
    sgemm<0, 1, true><<<dim3(4096), blk, 0, stream>>>(x2, fc1_w, fc1_b, nullptr, hb, 1024, 1024, 256, WSCALE);
    sgemm<1, 0, true><<<dim3(1024), blk, 0, stream>>>(hb, fc2_w, fc2_b, x2, tmp, 1024, 256, 1024, WSCALE);
    ln_f32<<<dim3(256), blk, 0, stream>>>(tmp, ln2_g, ln2_b, outx);
}

// Round 18
// 1547.236 us; speedup vs baseline: 4.9829x; 4.9829x over previous
//
#include <hip/hip_runtime.h>
#include <hip/hip_bf16.h>

#define BB 2
#define NN 512
#define LL 8192
#define CC 256
#define HH 8
#define DD 32
#define SCALE 0.17677669529663687f

typedef unsigned int u32;

__global__ void sentinel(float* out, float val) {
    if (threadIdx.x == 0) out[0] = val;
}

// ---------------------------------------------------------------------------
// Tiled f32 GEMM: C[M,N] = A[M,K] @ W[N,K]^T (+bias)(+res)(+gelu).
// 64x64 tile, 256 threads (16x16, 4x4 acc each), LDS [kk][row] layout so the
// inner loop is two ds_read_b128 + 16 FMA per kk.
// ---------------------------------------------------------------------------
template <int RES, int ACT, bool HAS_BIAS>
__global__ __launch_bounds__(256) void sgemm_t(
    const float* __restrict__ A, const float* __restrict__ W,
    const float* __restrict__ bias, const float* __restrict__ res,
    float* __restrict__ C, int M, int N, int K)
{
    __shared__ float As[32][68], Ws[32][68];   // [kk][row], pad 68 (f4-aligned)
    int t = threadIdx.x;
    int ty = t >> 4, tx = t & 15;
    int m0 = blockIdx.x * 64, n0 = blockIdx.y * 64;
    float acc[4][4] = {};
    for (int k0 = 0; k0 < K; k0 += 32) {
#pragma unroll
        for (int j = 0; j < 2; ++j) {
            int idx = t + j * 256;               // 512 float4 loads per operand
            int row = idx >> 3, c4 = idx & 7;
            float4 av = *(const float4*)&A[(size_t)(m0 + row) * K + k0 + c4 * 4];
            As[c4 * 4 + 0][row] = av.x; As[c4 * 4 + 1][row] = av.y;
            As[c4 * 4 + 2][row] = av.z; As[c4 * 4 + 3][row] = av.w;
            float4 wv = *(const float4*)&W[(size_t)(n0 + row) * K + k0 + c4 * 4];
            Ws[c4 * 4 + 0][row] = wv.x; Ws[c4 * 4 + 1][row] = wv.y;
            Ws[c4 * 4 + 2][row] = wv.z; Ws[c4 * 4 + 3][row] = wv.w;
        }
        __syncthreads();
#pragma unroll
        for (int kk = 0; kk < 32; ++kk) {
            float4 av = *(const float4*)&As[kk][ty * 4];
            float4 wv = *(const float4*)&Ws[kk][tx * 4];
            float a_[4] = {av.x, av.y, av.z, av.w};
            float w_[4] = {wv.x, wv.y, wv.z, wv.w};
#pragma unroll
            for (int r = 0; r < 4; ++r)
#pragma unroll
                for (int c = 0; c < 4; ++c)
                    acc[r][c] += a_[r] * w_[c];
        }
        __syncthreads();
    }
#pragma unroll
    for (int r = 0; r < 4; ++r) {
        int row = m0 + ty * 4 + r;
#pragma unroll
        for (int c = 0; c < 4; ++c) {
            int col = n0 + tx * 4 + c;
            float v = acc[r][c];
            if (HAS_BIAS) v += bias[col];
            if (RES) v += res[(size_t)row * N + col];
            if (ACT) v = 0.5f * v * (1.f + erff(v * 0.70710678118f));
            C[(size_t)row * N + col] = v;
        }
    }
}

// ---------------------------------------------------------------------------
// Flash attention, f32, LDS-staged. Block = 8 q-rows x 1 head x 1 batch.
// Per 32-l tile: stage K,V (coalesced) -> QK by thread (q, l) -> in-wave
// 32-lane softmax reduce -> p via LDS -> PV by thread (q, d). The (q,l) and
// (q,d) phases are the same thread (x = t&31), so m/s/alpha stay in regs.
// ---------------------------------------------------------------------------
__global__ __launch_bounds__(256) void attn_flash(
    const float* __restrict__ qp, const float* __restrict__ kp,
    const float* __restrict__ vp, float* __restrict__ op,
    int Lk, int qStride, int kStride, int Nq)
{
    __shared__ float qs[8][36], ks[32][36], vs[32][36], ps[8][36];
    int t = threadIdx.x;
    int qi = t >> 5, x = t & 31;
    int b = blockIdx.z, h = blockIdx.y;
    int n0 = blockIdx.x * 8;
    qs[qi][x] = qp[((size_t)b * Nq + n0 + qi) * qStride + h * DD + x];
    __syncthreads();
    float m = -1e30f, s_run = 0.f, o_acc = 0.f;
    const float* kb = kp + (size_t)b * Lk * kStride + h * DD;
    const float* vb = vp + (size_t)b * Lk * kStride + h * DD;
    for (int l0 = 0; l0 < Lk; l0 += 32) {
#pragma unroll
        for (int i = t; i < 1024; i += 256) {
            int r = i >> 5, d = i & 31;
            ks[r][d] = kb[(size_t)(l0 + r) * kStride + d];
            vs[r][d] = vb[(size_t)(l0 + r) * kStride + d];
        }
        __syncthreads();
        float dot = 0.f;
#pragma unroll
        for (int d4 = 0; d4 < 32; d4 += 4) {
            float4 qv = *(const float4*)&qs[qi][d4];
            float4 kv = *(const float4*)&ks[x][d4];
            dot += qv.x * kv.x + qv.y * kv.y + qv.z * kv.z + qv.w * kv.w;
        }
        dot *= SCALE;
        float mx = dot;
#pragma unroll
        for (int mk = 16; mk >= 1; mk >>= 1) mx = fmaxf(mx, __shfl_xor(mx, mk));
        float mn = fmaxf(m, mx);
        float alpha = __expf(m - mn);
        float p = __expf(dot - mn);
        float ts = p;
#pragma unroll
        for (int mk = 16; mk >= 1; mk >>= 1) ts += __shfl_xor(ts, mk);
        s_run = s_run * alpha + ts;
        m = mn;
        ps[qi][x] = p;
        __syncthreads();
        float acc = 0.f;
#pragma unroll
        for (int l = 0; l < 32; ++l)
            acc += ps[qi][l] * vs[l][x];
        o_acc = o_acc * alpha + acc;
        __syncthreads();
    }
    op[((size_t)b * Nq + n0 + qi) * CC + h * DD + x] = o_acc / s_run;
}

// ---------------------------------------------------------------------------
// Mask, f32, LDS-tiled: block = 8 n x 32 l; kc tile staged once (coalesced),
// reused by all 8 n. Thread = one (n, l): 8 head-dots from LDS + 8->8->1 MLP.
// ---------------------------------------------------------------------------
__global__ __launch_bounds__(256) void smask2(
    const float* __restrict__ qc, const float* __restrict__ kc,
    const float* __restrict__ w1, const float* __restrict__ b1,
    const float* __restrict__ w2, const float* __restrict__ b2,
    float* __restrict__ mout)
{
    __shared__ float ks[32][257];
    __shared__ float qs[8][257];
    int t = threadIdx.x;
    int l0 = blockIdx.x * 32, n0 = blockIdx.y * 8;
    for (int i = t; i < 32 * 256; i += 256)
        ks[i >> 8][i & 255] = kc[(size_t)(l0 + (i >> 8)) * CC + (i & 255)];
    for (int i = t; i < 8 * 256; i += 256)
        qs[i >> 8][i & 255] = qc[(size_t)(n0 + (i >> 8)) * CC + (i & 255)];
    __syncthreads();
    int n = t >> 5, lx = t & 31;
    float s[8];
#pragma unroll
    for (int h = 0; h < 8; ++h) {
        float d = 0.f;
#pragma unroll
        for (int dd = 0; dd < 32; ++dd)
            d += qs[n][h * 32 + dd] * ks[lx][h * 32 + dd];
        s[h] = d * SCALE;
    }
    float acc2 = b2[0];
#pragma unroll
    for (int o = 0; o < 8; ++o) {
        float f = b1[o];
#pragma unroll
        for (int i = 0; i < 8; ++i) f += s[i] * w1[o * 8 + i];
        f = fmaxf(f, 0.f);
        acc2 += f * w2[o];
    }
    mout[(size_t)(n0 + n) * LL + l0 + lx] = fmaxf(acc2, 0.f);
}

// ---------------------------------------------------------------------------
// f32 LayerNorm over C=256, one wave per row, f32 out (proven r17 kernel).
// ---------------------------------------------------------------------------
__global__ __launch_bounds__(256) void ln_f32(
    const float* __restrict__ a, const float* __restrict__ g,
    const float* __restrict__ be, float* __restrict__ out)
{
    int lane = threadIdx.x & 63, wave = threadIdx.x >> 6;
    int row = blockIdx.x * 4 + wave;
    float4 v = *(const float4*)(a + (size_t)row * CC + lane * 4);
    float sum = v.x + v.y + v.z + v.w;
    float sq = v.x * v.x + v.y * v.y + v.z * v.z + v.w * v.w;
#pragma unroll
    for (int mk = 1; mk < 64; mk <<= 1) {
        sum += __shfl_xor(sum, mk);
        sq += __shfl_xor(sq, mk);
    }
    float mean = sum * (1.f / 256.f);
    float var = sq * (1.f / 256.f) - mean * mean;
    float rstd = rsqrtf(var + 1e-5f);
    int c = lane * 4;
    float4 ov;
    ov.x = (v.x - mean) * rstd * g[c + 0] + be[c + 0];
    ov.y = (v.y - mean) * rstd * g[c + 1] + be[c + 1];
    ov.z = (v.z - mean) * rstd * g[c + 2] + be[c + 2];
    ov.w = (v.w - mean) * rstd * g[c + 3] + be[c + 3];
    *(float4*)(out + (size_t)row * CC + c) = ov;
}

// ---------------------------------------------------------------------------
extern "C" void kernel_launch(void* const* d_in, const int* in_sizes, int n_in,
                              void* d_out, int out_size, void* d_ws, size_t ws_size,
                              hipStream_t stream)
{
    (void)in_sizes; (void)n_in; (void)out_size;
    float* outx = (float*)d_out;                 // x: f32, 262144
    float* outm = outx + (size_t)BB * NN * CC;   // mask: f32, 8388608

    const float* query     = (const float*)d_in[0];
    const float* key       = (const float*)d_in[1];
    const float* value     = (const float*)d_in[2];
    const float* sa_qkv_w  = (const float*)d_in[3];
    const float* sa_proj_w = (const float*)d_in[4];
    const float* sa_proj_b = (const float*)d_in[5];
    const float* norm3_g   = (const float*)d_in[6];
    const float* norm3_b   = (const float*)d_in[7];
    const float* q_w       = (const float*)d_in[8];
    const float* k_w       = (const float*)d_in[9];
    const float* v_w       = (const float*)d_in[10];
    const float* ca_proj_w = (const float*)d_in[11];
    const float* ca_proj_b = (const float*)d_in[12];
    const float* l1_w      = (const float*)d_in[13];
    const float* l1_b      = (const float*)d_in[14];
    const float* l2_w      = (const float*)d_in[15];
    const float* l2_b      = (const float*)d_in[16];
    const float* ln1_g     = (const float*)d_in[17];
    const float* ln1_b     = (const float*)d_in[18];
    const float* ln2_g     = (const float*)d_in[19];
    const float* ln2_b     = (const float*)d_in[20];
    const float* fc1_w     = (const float*)d_in[21];
    const float* fc1_b     = (const float*)d_in[22];
    const float* fc2_w     = (const float*)d_in[23];
    const float* fc2_b     = (const float*)d_in[24];

    char* w0 = (char*)d_ws;
    float* unionA = (float*)w0;        w0 += (size_t)16 * 1024 * 1024;
    float* saH = (float*)w0;           w0 += (size_t)1024 * 256 * 4;
    float* x1  = (float*)w0;           w0 += (size_t)1024 * 256 * 4;
    float* x2  = (float*)w0;           w0 += (size_t)1024 * 256 * 4;
    float* tmp = (float*)w0;           w0 += (size_t)1024 * 256 * 4;
    float* qc  = (float*)w0;           w0 += (size_t)1024 * 256 * 4;
    float* caH = (float*)w0;           w0 += (size_t)1024 * 256 * 4;
    size_t need = (size_t)(w0 - (char*)d_ws);
    float* qkv = unionA;                        // phase 1: 1024 x 768
    float* kcb = unionA;                        // phase 2 (per b): 8192 x 256
    float* vcb = unionA + (size_t)8192 * 256;   //                  8192 x 256
    float* hb  = unionA;                        // phase 3: 1024 x 1024

    if (ws_size < need) {
        sentinel<<<dim3(1), dim3(64), 0, stream>>>(outx, 1000.f + (float)(ws_size >> 20));
        return;
    }

    dim3 blk(256);

    // 1. qkv = query @ sa_qkv_w.T (1024x768, K=256)
    sgemm_t<0, 0, false><<<dim3(16, 12), blk, 0, stream>>>(query, sa_qkv_w, nullptr, nullptr, qkv, 1024, 768, 256);
    // 2. self attention -> saH
    attn_flash<<<dim3(64, 8, 2), blk, 0, stream>>>(qkv, qkv + 256, qkv + 512, saH, 512, 768, 768, 512);
    // 3. sa proj + bias + residual(query) -> tmp
    sgemm_t<1, 0, true><<<dim3(16, 4), blk, 0, stream>>>(saH, sa_proj_w, sa_proj_b, query, tmp, 1024, 256, 256);
    // 4. LN(norm3) -> x1
    ln_f32<<<dim3(256), blk, 0, stream>>>(tmp, norm3_g, norm3_b, x1);
    // 5. qc = x1 @ q_w.T
    sgemm_t<0, 0, false><<<dim3(16, 4), blk, 0, stream>>>(x1, q_w, nullptr, nullptr, qc, 1024, 256, 256);
    // 6-9. per-batch: kc, vc, cross attention, mask
    for (int b = 0; b < 2; ++b) {
        const float* keyb = key + (size_t)b * 8192 * 256;
        const float* valb = value + (size_t)b * 8192 * 256;
        sgemm_t<0, 0, false><<<dim3(128, 4), blk, 0, stream>>>(keyb, k_w, nullptr, nullptr, kcb, 8192, 256, 256);
        sgemm_t<0, 0, false><<<dim3(128, 4), blk, 0, stream>>>(valb, v_w, nullptr, nullptr, vcb, 8192, 256, 256);
        attn_flash<<<dim3(64, 8, 1), blk, 0, stream>>>(qc + (size_t)b * 512 * 256, kcb, vcb,
                                                       caH + (size_t)b * 512 * 256, 8192, 256, 256, 512);
        smask2<<<dim3(256, 64), blk, 0, stream>>>(qc + (size_t)b * 512 * 256, kcb,
                                                  l1_w, l1_b, l2_w, l2_b,
                                                  outm + (size_t)b * 512 * 8192);
    }
    // 10. ca proj + bias + residual(x1) -> tmp
    sgemm_t<1, 0, true><<<dim3(16, 4), blk, 0, stream>>>(caH, ca_proj_w, ca_proj_b, x1, tmp, 1024, 256, 256);
    // 11. LN(ln1) -> x2
    ln_f32<<<dim3(256), blk, 0, stream>>>(tmp, ln1_g, ln1_b, x2);
    // 12. fc1 + bias + exact GELU -> hb (1024x1024)
    sgemm_t<0, 1, true><<<dim3(16, 16), blk, 0, stream>>>(x2, fc1_w, fc1_b, nullptr, hb, 1024, 1024, 256);
    // 13. fc2 + bias + residual(x2) -> tmp (K=1024)
    sgemm_t<1, 0, true><<<dim3(16, 4), blk, 0, stream>>>(hb, fc2_w, fc2_b, x2, tmp, 1024, 256, 1024);
    // 14. LN(ln2) -> outx
    ln_f32<<<dim3(256), blk, 0, stream>>>(tmp, ln2_g, ln2_b, outx);
}

// Round 19
// 1175.166 us; speedup vs baseline: 6.5605x; 1.3166x over previous
//
#include <hip/hip_runtime.h>
#include <hip/hip_bf16.h>

#define BB 2
#define NN 512
#define LL 8192
#define CC 256
#define HH 8
#define DD 32
#define SCALE 0.17677669529663687f

typedef unsigned int u32;

__global__ void sentinel(float* out, float val) {
    if (threadIdx.x == 0) out[0] = val;
}

// ---------------------------------------------------------------------------
// Tiled f32 GEMM: C[M,N] = A[M,K] @ W[N,K]^T (+bias)(+res)(+gelu).
// 64x64 tile, 256 threads, LDS [kk][row] layout. (r18 proven)
// ---------------------------------------------------------------------------
template <int RES, int ACT, bool HAS_BIAS>
__global__ __launch_bounds__(256) void sgemm_t(
    const float* __restrict__ A, const float* __restrict__ W,
    const float* __restrict__ bias, const float* __restrict__ res,
    float* __restrict__ C, int M, int N, int K)
{
    __shared__ float As[32][68], Ws[32][68];
    int t = threadIdx.x;
    int ty = t >> 4, tx = t & 15;
    int m0 = blockIdx.x * 64, n0 = blockIdx.y * 64;
    float acc[4][4] = {};
    for (int k0 = 0; k0 < K; k0 += 32) {
#pragma unroll
        for (int j = 0; j < 2; ++j) {
            int idx = t + j * 256;
            int row = idx >> 3, c4 = idx & 7;
            float4 av = *(const float4*)&A[(size_t)(m0 + row) * K + k0 + c4 * 4];
            As[c4 * 4 + 0][row] = av.x; As[c4 * 4 + 1][row] = av.y;
            As[c4 * 4 + 2][row] = av.z; As[c4 * 4 + 3][row] = av.w;
            float4 wv = *(const float4*)&W[(size_t)(n0 + row) * K + k0 + c4 * 4];
            Ws[c4 * 4 + 0][row] = wv.x; Ws[c4 * 4 + 1][row] = wv.y;
            Ws[c4 * 4 + 2][row] = wv.z; Ws[c4 * 4 + 3][row] = wv.w;
        }
        __syncthreads();
#pragma unroll
        for (int kk = 0; kk < 32; ++kk) {
            float4 av = *(const float4*)&As[kk][ty * 4];
            float4 wv = *(const float4*)&Ws[kk][tx * 4];
            float a_[4] = {av.x, av.y, av.z, av.w};
            float w_[4] = {wv.x, wv.y, wv.z, wv.w};
#pragma unroll
            for (int r = 0; r < 4; ++r)
#pragma unroll
                for (int c = 0; c < 4; ++c)
                    acc[r][c] += a_[r] * w_[c];
        }
        __syncthreads();
    }
#pragma unroll
    for (int r = 0; r < 4; ++r) {
        int row = m0 + ty * 4 + r;
#pragma unroll
        for (int c = 0; c < 4; ++c) {
            int col = n0 + tx * 4 + c;
            float v = acc[r][c];
            if (HAS_BIAS) v += bias[col];
            if (RES) v += res[(size_t)row * N + col];
            if (ACT) v = 0.5f * v * (1.f + erff(v * 0.70710678118f));
            C[(size_t)row * N + col] = v;
        }
    }
}

// ---------------------------------------------------------------------------
// Flash attention, full-L (used for self-attn; r18 proven).
// ---------------------------------------------------------------------------
__global__ __launch_bounds__(256) void attn_flash(
    const float* __restrict__ qp, const float* __restrict__ kp,
    const float* __restrict__ vp, float* __restrict__ op,
    int Lk, int qStride, int kStride, int Nq)
{
    __shared__ float qs[8][36], ks[32][36], vs[32][36], ps[8][36];
    int t = threadIdx.x;
    int qi = t >> 5, x = t & 31;
    int b = blockIdx.z, h = blockIdx.y;
    int n0 = blockIdx.x * 8;
    qs[qi][x] = qp[((size_t)b * Nq + n0 + qi) * qStride + h * DD + x];
    __syncthreads();
    float m = -1e30f, s_run = 0.f, o_acc = 0.f;
    const float* kb = kp + (size_t)b * Lk * kStride + h * DD;
    const float* vb = vp + (size_t)b * Lk * kStride + h * DD;
    for (int l0 = 0; l0 < Lk; l0 += 32) {
#pragma unroll
        for (int i = t; i < 1024; i += 256) {
            int r = i >> 5, d = i & 31;
            ks[r][d] = kb[(size_t)(l0 + r) * kStride + d];
            vs[r][d] = vb[(size_t)(l0 + r) * kStride + d];
        }
        __syncthreads();
        float dot = 0.f;
#pragma unroll
        for (int d4 = 0; d4 < 32; d4 += 4) {
            float4 qv = *(const float4*)&qs[qi][d4];
            float4 kv = *(const float4*)&ks[x][d4];
            dot += qv.x * kv.x + qv.y * kv.y + qv.z * kv.z + qv.w * kv.w;
        }
        dot *= SCALE;
        float mx = dot;
#pragma unroll
        for (int mk = 16; mk >= 1; mk >>= 1) mx = fmaxf(mx, __shfl_xor(mx, mk));
        float mn = fmaxf(m, mx);
        float alpha = __expf(m - mn);
        float p = __expf(dot - mn);
        float ts = p;
#pragma unroll
        for (int mk = 16; mk >= 1; mk >>= 1) ts += __shfl_xor(ts, mk);
        s_run = s_run * alpha + ts;
        m = mn;
        ps[qi][x] = p;
        __syncthreads();
        float acc = 0.f;
#pragma unroll
        for (int l = 0; l < 32; ++l)
            acc += ps[qi][l] * vs[l][x];
        o_acc = o_acc * alpha + acc;
        __syncthreads();
    }
    op[((size_t)b * Nq + n0 + qi) * CC + h * DD + x] = o_acc / s_run;
}

// ---------------------------------------------------------------------------
// Flash attention with L-split: blockIdx.z = split (gridDim.z splits).
// qp/kp/vp/outputs pre-offset per batch. Writes PARTIALS:
//   po[split][n][h*DD+d] = o_acc (unnormalized), pm/ps[split][n][h] = m, s.
// ---------------------------------------------------------------------------
__global__ __launch_bounds__(256) void attn_flash_sp(
    const float* __restrict__ qp, const float* __restrict__ kp,
    const float* __restrict__ vp, float* __restrict__ po,
    float* __restrict__ pm, float* __restrict__ ps_,
    int Lk, int qStride, int kStride, int Nq)
{
    __shared__ float qs[8][36], ks[32][36], vs[32][36], ps[8][36];
    int t = threadIdx.x;
    int qi = t >> 5, x = t & 31;
    int h = blockIdx.y, split = blockIdx.z;
    int n0 = blockIdx.x * 8;
    int chunk = Lk / gridDim.z;
    int lbeg = split * chunk, lend = lbeg + chunk;
    qs[qi][x] = qp[(size_t)(n0 + qi) * qStride + h * DD + x];
    __syncthreads();
    float m = -1e30f, s_run = 0.f, o_acc = 0.f;
    const float* kb = kp + h * DD;
    const float* vb = vp + h * DD;
    for (int l0 = lbeg; l0 < lend; l0 += 32) {
#pragma unroll
        for (int i = t; i < 1024; i += 256) {
            int r = i >> 5, d = i & 31;
            ks[r][d] = kb[(size_t)(l0 + r) * kStride + d];
            vs[r][d] = vb[(size_t)(l0 + r) * kStride + d];
        }
        __syncthreads();
        float dot = 0.f;
#pragma unroll
        for (int d4 = 0; d4 < 32; d4 += 4) {
            float4 qv = *(const float4*)&qs[qi][d4];
            float4 kv = *(const float4*)&ks[x][d4];
            dot += qv.x * kv.x + qv.y * kv.y + qv.z * kv.z + qv.w * kv.w;
        }
        dot *= SCALE;
        float mx = dot;
#pragma unroll
        for (int mk = 16; mk >= 1; mk >>= 1) mx = fmaxf(mx, __shfl_xor(mx, mk));
        float mn = fmaxf(m, mx);
        float alpha = __expf(m - mn);
        float p = __expf(dot - mn);
        float ts = p;
#pragma unroll
        for (int mk = 16; mk >= 1; mk >>= 1) ts += __shfl_xor(ts, mk);
        s_run = s_run * alpha + ts;
        m = mn;
        ps[qi][x] = p;
        __syncthreads();
        float acc = 0.f;
#pragma unroll
        for (int l = 0; l < 32; ++l)
            acc += ps[qi][l] * vs[l][x];
        o_acc = o_acc * alpha + acc;
        __syncthreads();
    }
    int n = n0 + qi;
    po[((size_t)split * Nq + n) * CC + h * DD + x] = o_acc;
    if (x == 0) {
        pm[((size_t)split * Nq + n) * HH + h] = m;
        ps_[((size_t)split * Nq + n) * HH + h] = s_run;
    }
}

// ---------------------------------------------------------------------------
// Combine nsplit flash partials -> normalized output (pre-offset per batch).
// ---------------------------------------------------------------------------
__global__ __launch_bounds__(256) void attn_combine(
    const float* __restrict__ po, const float* __restrict__ pm,
    const float* __restrict__ ps, float* __restrict__ out,
    int Nq, int nsplit)
{
    int idx = blockIdx.x * 256 + threadIdx.x;
    if (idx >= Nq * CC) return;
    int n = idx >> 8, cd = idx & 255;
    int h = cd >> 5;
    float mm = -1e30f;
    for (int z = 0; z < nsplit; ++z)
        mm = fmaxf(mm, pm[((size_t)z * Nq + n) * HH + h]);
    float num = 0.f, den = 0.f;
    for (int z = 0; z < nsplit; ++z) {
        float e = __expf(pm[((size_t)z * Nq + n) * HH + h] - mm);
        num += e * po[((size_t)z * Nq + n) * CC + cd];
        den += e * ps[((size_t)z * Nq + n) * HH + h];
    }
    out[(size_t)n * CC + cd] = num / den;
}

// ---------------------------------------------------------------------------
// Mask, f32, LDS-tiled (r18 proven).
// ---------------------------------------------------------------------------
__global__ __launch_bounds__(256) void smask2(
    const float* __restrict__ qc, const float* __restrict__ kc,
    const float* __restrict__ w1, const float* __restrict__ b1,
    const float* __restrict__ w2, const float* __restrict__ b2,
    float* __restrict__ mout)
{
    __shared__ float ks[32][257];
    __shared__ float qs[8][257];
    int t = threadIdx.x;
    int l0 = blockIdx.x * 32, n0 = blockIdx.y * 8;
    for (int i = t; i < 32 * 256; i += 256)
        ks[i >> 8][i & 255] = kc[(size_t)(l0 + (i >> 8)) * CC + (i & 255)];
    for (int i = t; i < 8 * 256; i += 256)
        qs[i >> 8][i & 255] = qc[(size_t)(n0 + (i >> 8)) * CC + (i & 255)];
    __syncthreads();
    int n = t >> 5, lx = t & 31;
    float s[8];
#pragma unroll
    for (int h = 0; h < 8; ++h) {
        float d = 0.f;
#pragma unroll
        for (int dd = 0; dd < 32; ++dd)
            d += qs[n][h * 32 + dd] * ks[lx][h * 32 + dd];
        s[h] = d * SCALE;
    }
    float acc2 = b2[0];
#pragma unroll
    for (int o = 0; o < 8; ++o) {
        float f = b1[o];
#pragma unroll
        for (int i = 0; i < 8; ++i) f += s[i] * w1[o * 8 + i];
        f = fmaxf(f, 0.f);
        acc2 += f * w2[o];
    }
    mout[(size_t)(n0 + n) * LL + l0 + lx] = fmaxf(acc2, 0.f);
}

// ---------------------------------------------------------------------------
// f32 LayerNorm over C=256 (r17 proven).
// ---------------------------------------------------------------------------
__global__ __launch_bounds__(256) void ln_f32(
    const float* __restrict__ a, const float* __restrict__ g,
    const float* __restrict__ be, float* __restrict__ out)
{
    int lane = threadIdx.x & 63, wave = threadIdx.x >> 6;
    int row = blockIdx.x * 4 + wave;
    float4 v = *(const float4*)(a + (size_t)row * CC + lane * 4);
    float sum = v.x + v.y + v.z + v.w;
    float sq = v.x * v.x + v.y * v.y + v.z * v.z + v.w * v.w;
#pragma unroll
    for (int mk = 1; mk < 64; mk <<= 1) {
        sum += __shfl_xor(sum, mk);
        sq += __shfl_xor(sq, mk);
    }
    float mean = sum * (1.f / 256.f);
    float var = sq * (1.f / 256.f) - mean * mean;
    float rstd = rsqrtf(var + 1e-5f);
    int c = lane * 4;
    float4 ov;
    ov.x = (v.x - mean) * rstd * g[c + 0] + be[c + 0];
    ov.y = (v.y - mean) * rstd * g[c + 1] + be[c + 1];
    ov.z = (v.z - mean) * rstd * g[c + 2] + be[c + 2];
    ov.w = (v.w - mean) * rstd * g[c + 3] + be[c + 3];
    *(float4*)(out + (size_t)row * CC + c) = ov;
}

// ---------------------------------------------------------------------------
extern "C" void kernel_launch(void* const* d_in, const int* in_sizes, int n_in,
                              void* d_out, int out_size, void* d_ws, size_t ws_size,
                              hipStream_t stream)
{
    (void)in_sizes; (void)n_in; (void)out_size;
    float* outx = (float*)d_out;
    float* outm = outx + (size_t)BB * NN * CC;

    const float* query     = (const float*)d_in[0];
    const float* key       = (const float*)d_in[1];
    const float* value     = (const float*)d_in[2];
    const float* sa_qkv_w  = (const float*)d_in[3];
    const float* sa_proj_w = (const float*)d_in[4];
    const float* sa_proj_b = (const float*)d_in[5];
    const float* norm3_g   = (const float*)d_in[6];
    const float* norm3_b   = (const float*)d_in[7];
    const float* q_w       = (const float*)d_in[8];
    const float* k_w       = (const float*)d_in[9];
    const float* v_w       = (const float*)d_in[10];
    const float* ca_proj_w = (const float*)d_in[11];
    const float* ca_proj_b = (const float*)d_in[12];
    const float* l1_w      = (const float*)d_in[13];
    const float* l1_b      = (const float*)d_in[14];
    const float* l2_w      = (const float*)d_in[15];
    const float* l2_b      = (const float*)d_in[16];
    const float* ln1_g     = (const float*)d_in[17];
    const float* ln1_b     = (const float*)d_in[18];
    const float* ln2_g     = (const float*)d_in[19];
    const float* ln2_b     = (const float*)d_in[20];
    const float* fc1_w     = (const float*)d_in[21];
    const float* fc1_b     = (const float*)d_in[22];
    const float* fc2_w     = (const float*)d_in[23];
    const float* fc2_b     = (const float*)d_in[24];

    const int NSPLIT = 4;

    char* w0 = (char*)d_ws;
    float* unionA = (float*)w0;        w0 += (size_t)16 * 1024 * 1024;
    float* saH = (float*)w0;           w0 += (size_t)1024 * 256 * 4;
    float* x1  = (float*)w0;           w0 += (size_t)1024 * 256 * 4;
    float* x2  = (float*)w0;           w0 += (size_t)1024 * 256 * 4;
    float* tmp = (float*)w0;           w0 += (size_t)1024 * 256 * 4;
    float* qc  = (float*)w0;           w0 += (size_t)1024 * 256 * 4;
    float* caH = (float*)w0;           w0 += (size_t)1024 * 256 * 4;
    float* po  = (float*)w0;           w0 += (size_t)NSPLIT * 512 * 256 * 4;  // 2 MB
    float* pm  = (float*)w0;           w0 += (size_t)NSPLIT * 512 * 8 * 4;
    float* ps  = (float*)w0;           w0 += (size_t)NSPLIT * 512 * 8 * 4;
    size_t need = (size_t)(w0 - (char*)d_ws);
    float* qkv = unionA;
    float* kcb = unionA;
    float* vcb = unionA + (size_t)8192 * 256;
    float* hb  = unionA;

    if (ws_size < need) {
        sentinel<<<dim3(1), dim3(64), 0, stream>>>(outx, 1000.f + (float)(ws_size >> 20));
        return;
    }

    dim3 blk(256);

    // 1. qkv = query @ sa_qkv_w.T (1024x768, K=256)
    sgemm_t<0, 0, false><<<dim3(16, 12), blk, 0, stream>>>(query, sa_qkv_w, nullptr, nullptr, qkv, 1024, 768, 256);
    // 2. self attention -> saH
    attn_flash<<<dim3(64, 8, 2), blk, 0, stream>>>(qkv, qkv + 256, qkv + 512, saH, 512, 768, 768, 512);
    // 3. sa proj + bias + residual(query) -> tmp
    sgemm_t<1, 0, true><<<dim3(16, 4), blk, 0, stream>>>(saH, sa_proj_w, sa_proj_b, query, tmp, 1024, 256, 256);
    // 4. LN(norm3) -> x1
    ln_f32<<<dim3(256), blk, 0, stream>>>(tmp, norm3_g, norm3_b, x1);
    // 5. qc = x1 @ q_w.T
    sgemm_t<0, 0, false><<<dim3(16, 4), blk, 0, stream>>>(x1, q_w, nullptr, nullptr, qc, 1024, 256, 256);
    // 6-9. per-batch: kc, vc, cross attention (L-split x4 + combine), mask
    for (int b = 0; b < 2; ++b) {
        const float* keyb = key + (size_t)b * 8192 * 256;
        const float* valb = value + (size_t)b * 8192 * 256;
        const float* qcb = qc + (size_t)b * 512 * 256;
        sgemm_t<0, 0, false><<<dim3(128, 4), blk, 0, stream>>>(keyb, k_w, nullptr, nullptr, kcb, 8192, 256, 256);
        sgemm_t<0, 0, false><<<dim3(128, 4), blk, 0, stream>>>(valb, v_w, nullptr, nullptr, vcb, 8192, 256, 256);
        attn_flash_sp<<<dim3(64, 8, NSPLIT), blk, 0, stream>>>(qcb, kcb, vcb, po, pm, ps, 8192, 256, 256, 512);
        attn_combine<<<dim3(512), blk, 0, stream>>>(po, pm, ps, caH + (size_t)b * 512 * 256, 512, NSPLIT);
        smask2<<<dim3(256, 64), blk, 0, stream>>>(qcb, kcb, l1_w, l1_b, l2_w, l2_b,
                                                  outm + (size_t)b * 512 * 8192);
    }
    // 10. ca proj + bias + residual(x1) -> tmp
    sgemm_t<1, 0, true><<<dim3(16, 4), blk, 0, stream>>>(caH, ca_proj_w, ca_proj_b, x1, tmp, 1024, 256, 256);
    // 11. LN(ln1) -> x2
    ln_f32<<<dim3(256), blk, 0, stream>>>(tmp, ln1_g, ln1_b, x2);
    // 12. fc1 + bias + exact GELU -> hb
    sgemm_t<0, 1, true><<<dim3(16, 16), blk, 0, stream>>>(x2, fc1_w, fc1_b, nullptr, hb, 1024, 1024, 256);
    // 13. fc2 + bias + residual(x2) -> tmp
    sgemm_t<1, 0, true><<<dim3(16, 4), blk, 0, stream>>>(hb, fc2_w, fc2_b, x2, tmp, 1024, 256, 1024);
    // 14. LN(ln2) -> outx
    ln_f32<<<dim3(256), blk, 0, stream>>>(tmp, ln2_g, ln2_b, outx);
}

// Round 20
// 584.585 us; speedup vs baseline: 13.1882x; 2.0103x over previous
//
#include <hip/hip_runtime.h>
#include <hip/hip_bf16.h>

#define BB 2
#define NN 512
#define LL 8192
#define CC 256
#define HH 8
#define DD 32
#define SCALE 0.17677669529663687f

typedef unsigned short u16;
typedef unsigned int u32;
typedef __attribute__((ext_vector_type(8))) short bf16x8;
typedef __attribute__((ext_vector_type(4))) float f32x4;

__device__ __forceinline__ float bf2f(u16 v) { return __uint_as_float(((u32)v) << 16); }
__device__ __forceinline__ u16 f2bf(float f) {
    u32 u = __float_as_uint(f);
    return (u16)((u + 0x7fffu + ((u >> 16) & 1u)) >> 16);
}
__device__ __forceinline__ bf16x8 ld8(const u16* p) { return *(const bf16x8*)p; }

__global__ void sentinel(float* out, float val) {
    if (threadIdx.x == 0) out[0] = val;
}

// ---------------------------------------------------------------------------
// Tiled f32 GEMM, optional bf16 output copy. OUT: 0 = f32 only, 1 = bf16
// only, 2 = both. (r18-proven core.)
// ---------------------------------------------------------------------------
template <int RES, int ACT, bool HAS_BIAS, int OUT>
__global__ __launch_bounds__(256) void sgemm_t(
    const float* __restrict__ A, const float* __restrict__ W,
    const float* __restrict__ bias, const float* __restrict__ res,
    float* __restrict__ Cf, u16* __restrict__ Cb, int M, int N, int K)
{
    __shared__ float As[32][68], Ws[32][68];
    int t = threadIdx.x;
    int ty = t >> 4, tx = t & 15;
    int m0 = blockIdx.x * 64, n0 = blockIdx.y * 64;
    float acc[4][4] = {};
    for (int k0 = 0; k0 < K; k0 += 32) {
#pragma unroll
        for (int j = 0; j < 2; ++j) {
            int idx = t + j * 256;
            int row = idx >> 3, c4 = idx & 7;
            float4 av = *(const float4*)&A[(size_t)(m0 + row) * K + k0 + c4 * 4];
            As[c4 * 4 + 0][row] = av.x; As[c4 * 4 + 1][row] = av.y;
            As[c4 * 4 + 2][row] = av.z; As[c4 * 4 + 3][row] = av.w;
            float4 wv = *(const float4*)&W[(size_t)(n0 + row) * K + k0 + c4 * 4];
            Ws[c4 * 4 + 0][row] = wv.x; Ws[c4 * 4 + 1][row] = wv.y;
            Ws[c4 * 4 + 2][row] = wv.z; Ws[c4 * 4 + 3][row] = wv.w;
        }
        __syncthreads();
#pragma unroll
        for (int kk = 0; kk < 32; ++kk) {
            float4 av = *(const float4*)&As[kk][ty * 4];
            float4 wv = *(const float4*)&Ws[kk][tx * 4];
            float a_[4] = {av.x, av.y, av.z, av.w};
            float w_[4] = {wv.x, wv.y, wv.z, wv.w};
#pragma unroll
            for (int r = 0; r < 4; ++r)
#pragma unroll
                for (int c = 0; c < 4; ++c)
                    acc[r][c] += a_[r] * w_[c];
        }
        __syncthreads();
    }
#pragma unroll
    for (int r = 0; r < 4; ++r) {
        int row = m0 + ty * 4 + r;
#pragma unroll
        for (int c = 0; c < 4; ++c) {
            int col = n0 + tx * 4 + c;
            float v = acc[r][c];
            if (HAS_BIAS) v += bias[col];
            if (RES) v += res[(size_t)row * N + col];
            if (ACT) v = 0.5f * v * (1.f + erff(v * 0.70710678118f));
            if (OUT == 0 || OUT == 2) Cf[(size_t)row * N + col] = v;
            if (OUT == 1 || OUT == 2) Cb[(size_t)row * N + col] = f2bf(v);
        }
    }
}

// ---------------------------------------------------------------------------
// bf16 head-transpose: out[(h*DD+d)*vtL + r] = in[r*rowStride + h*DD + d].
// Per-batch via bStride offsets. grid (R/64, H, B).
// ---------------------------------------------------------------------------
__global__ __launch_bounds__(256) void transpose_bf(
    const u16* __restrict__ in, u16* __restrict__ out,
    int rowStride, int vtL, size_t bStrideIn, size_t bStrideOut)
{
    __shared__ alignas(16) u16 tl[64][33];
    int r0 = blockIdx.x * 64;
    int h = blockIdx.y, b = blockIdx.z;
    const u16* ip = in + (size_t)b * bStrideIn + h * DD;
    for (int i = threadIdx.x; i < 64 * 32; i += 256) {
        int r = i >> 5, d = i & 31;
        tl[r][d] = ip[(size_t)(r0 + r) * rowStride + d];
    }
    __syncthreads();
    u16* op = out + (size_t)b * bStrideOut + (size_t)h * DD * vtL + r0;
    for (int i = threadIdx.x; i < 64 * 32; i += 256) {
        int r = i & 63, d = i >> 6;
        op[(size_t)d * vtL + r] = tl[r][d];
    }
}

// ---------------------------------------------------------------------------
// MFMA flash attention (16x16x32 bf16, f32 accum). Block = 32 q x 1 head;
// 4 waves each own a contiguous L-chunk. Swapped QK: S^T = mfma(A=K, B=Q)
// so softmax-over-l stats are lane-local in q = lane&15. V pre-transposed
// (H,D,L). P routed via padded LDS (stride 48 u16 = 96B, 16B-aligned frags).
// SPLIT: blockIdx.z = L-split, writes partials (po=num, pm=m, ps=den);
// else blockIdx.z = batch, writes normalized output.
// ---------------------------------------------------------------------------
template <bool SPLIT>
__global__ __launch_bounds__(256) void attn_mfma(
    const u16* __restrict__ qp, const u16* __restrict__ kp,
    const u16* __restrict__ vt, float* __restrict__ outp,
    float* __restrict__ pm, float* __restrict__ ps_,
    int Lk, int qStride, int kStride, int vtL, int Nq)
{
    __shared__ alignas(16) u16 plds[4][32][48];
    __shared__ alignas(16) float comb[4][32][34];
    int lane = threadIdx.x & 63, wave = threadIdx.x >> 6;
    int lr = lane & 15, lg = lane >> 4;
    int h = blockIdx.y, n0 = blockIdx.x * 32, z = blockIdx.z;
    size_t qoff = 0, koff = 0, voff = 0;
    int lbeg, lend;
    if (SPLIT) {
        int chunk = Lk / (gridDim.z * 4);
        lbeg = z * (Lk / gridDim.z) + wave * chunk;
        lend = lbeg + chunk;
    } else {
        int chunk = Lk / 4;
        lbeg = wave * chunk;
        lend = lbeg + chunk;
        qoff = (size_t)z * Nq * qStride;
        koff = (size_t)z * Lk * kStride;
        voff = (size_t)z * HH * DD * vtL;
    }

    bf16x8 bq[2];
#pragma unroll
    for (int nh = 0; nh < 2; ++nh)
        bq[nh] = ld8(qp + qoff + (size_t)(n0 + nh * 16 + lr) * qStride + h * DD + lg * 8);

    f32x4 o[2][2] = {};
    float m = -1e30f, s = 0.f;       // per-lane stats for q = lr of tile nh -> track per nh
    float m2 = -1e30f, s2 = 0.f;
    const u16* kb = kp + koff + h * DD + lg * 8;
    const u16* vb0 = vt + voff + (size_t)h * DD * vtL;

    for (int l0 = lbeg; l0 < lend; l0 += 32) {
        bf16x8 ka[2];
#pragma unroll
        for (int lt = 0; lt < 2; ++lt)
            ka[lt] = ld8(kb + (size_t)(l0 + lt * 16 + lr) * kStride);
        f32x4 st[2][2];
#pragma unroll
        for (int lt = 0; lt < 2; ++lt)
#pragma unroll
            for (int nh = 0; nh < 2; ++nh) {
                f32x4 zz = {0.f, 0.f, 0.f, 0.f};
                st[lt][nh] = __builtin_amdgcn_mfma_f32_16x16x32_bf16(ka[lt], bq[nh], zz, 0, 0, 0);
            }
        float aq[2];
#pragma unroll
        for (int nh = 0; nh < 2; ++nh) {
            float mprev = (nh == 0) ? m : m2;
            float sprev = (nh == 0) ? s : s2;
            float mx = -1e30f;
#pragma unroll
            for (int lt = 0; lt < 2; ++lt)
#pragma unroll
                for (int r = 0; r < 4; ++r) {
                    float v = st[lt][nh][r] * SCALE;
                    st[lt][nh][r] = v;
                    mx = fmaxf(mx, v);
                }
            mx = fmaxf(mx, __shfl_xor(mx, 16));
            mx = fmaxf(mx, __shfl_xor(mx, 32));
            float mn = fmaxf(mprev, mx);
            float alpha = __expf(mprev - mn);
            float rs = 0.f;
#pragma unroll
            for (int lt = 0; lt < 2; ++lt) {
                u16 pk[4];
#pragma unroll
                for (int r = 0; r < 4; ++r) {
                    float p = __expf(st[lt][nh][r] - mn);
                    rs += p;
                    pk[r] = f2bf(p);
                }
                uint2 pv;
                pv.x = (u32)pk[0] | ((u32)pk[1] << 16);
                pv.y = (u32)pk[2] | ((u32)pk[3] << 16);
                *(uint2*)&plds[wave][nh * 16 + lr][lt * 16 + lg * 4] = pv;
            }
            rs += __shfl_xor(rs, 16);
            rs += __shfl_xor(rs, 32);
            if (nh == 0) { s = sprev * alpha + rs; m = mn; }
            else         { s2 = sprev * alpha + rs; m2 = mn; }
            aq[nh] = alpha;
        }
        // rescale accumulators: o row q_local = qt*16 + lg*4 + r; alpha at lane q_local (lg=0 copy)
#pragma unroll
        for (int qt = 0; qt < 2; ++qt)
#pragma unroll
            for (int r = 0; r < 4; ++r) {
                float al = __shfl(aq[qt], (lg << 2) + r);
                o[qt][0][r] *= al;
                o[qt][1][r] *= al;
            }
        asm volatile("" ::: "memory");
        bf16x8 pa[2], vv[2];
#pragma unroll
        for (int qt = 0; qt < 2; ++qt)
            pa[qt] = ld8(&plds[wave][qt * 16 + lr][lg * 8]);
        asm volatile("" ::: "memory");
#pragma unroll
        for (int dt = 0; dt < 2; ++dt)
            vv[dt] = ld8(vb0 + (size_t)(dt * 16 + lr) * vtL + l0 + lg * 8);
#pragma unroll
        for (int qt = 0; qt < 2; ++qt)
#pragma unroll
            for (int dt = 0; dt < 2; ++dt)
                o[qt][dt] = __builtin_amdgcn_mfma_f32_16x16x32_bf16(pa[qt], vv[dt], o[qt][dt], 0, 0, 0);
    }

    // stash per-wave results
#pragma unroll
    for (int qt = 0; qt < 2; ++qt)
#pragma unroll
        for (int dt = 0; dt < 2; ++dt)
#pragma unroll
            for (int r = 0; r < 4; ++r)
                comb[wave][qt * 16 + lg * 4 + r][dt * 16 + lr] = o[qt][dt][r];
    if (lg == 0) {
        comb[wave][lr][32] = m;       comb[wave][lr][33] = s;
        comb[wave][16 + lr][32] = m2; comb[wave][16 + lr][33] = s2;
    }
    __syncthreads();
    for (int idx = threadIdx.x; idx < 1024; idx += 256) {
        int q2 = idx >> 5, d = idx & 31;
        float mm = -1e30f;
#pragma unroll
        for (int w = 0; w < 4; ++w) mm = fmaxf(mm, comb[w][q2][32]);
        float num = 0.f, den = 0.f;
#pragma unroll
        for (int w = 0; w < 4; ++w) {
            float e = __expf(comb[w][q2][32] - mm);
            num += e * comb[w][q2][d];
            den += e * comb[w][q2][33];
        }
        int n = n0 + q2;
        if (SPLIT) {
            outp[((size_t)z * Nq + n) * CC + h * DD + d] = num;
            if (d == 0) {
                pm[((size_t)z * Nq + n) * HH + h] = mm;
                ps_[((size_t)z * Nq + n) * HH + h] = den;
            }
        } else {
            outp[((size_t)z * Nq + n) * CC + h * DD + d] = num / den;
        }
    }
}

// ---------------------------------------------------------------------------
// Combine nsplit flash partials (po=num, pm=m, ps=den) -> normalized out.
// ---------------------------------------------------------------------------
__global__ __launch_bounds__(256) void attn_combine(
    const float* __restrict__ po, const float* __restrict__ pm,
    const float* __restrict__ ps, float* __restrict__ out,
    int Nq, int nsplit)
{
    int idx = blockIdx.x * 256 + threadIdx.x;
    if (idx >= Nq * CC) return;
    int n = idx >> 8, cd = idx & 255;
    int h = cd >> 5;
    float mm = -1e30f;
    for (int zz = 0; zz < nsplit; ++zz)
        mm = fmaxf(mm, pm[((size_t)zz * Nq + n) * HH + h]);
    float num = 0.f, den = 0.f;
    for (int zz = 0; zz < nsplit; ++zz) {
        float e = __expf(pm[((size_t)zz * Nq + n) * HH + h] - mm);
        num += e * po[((size_t)zz * Nq + n) * CC + cd];
        den += e * ps[((size_t)zz * Nq + n) * HH + h];
    }
    out[(size_t)n * CC + cd] = num / den;
}

// ---------------------------------------------------------------------------
// Mask: qc f32 + kc bf16, LDS-tiled (r18-proven structure).
// ---------------------------------------------------------------------------
__global__ __launch_bounds__(256) void smask2(
    const float* __restrict__ qc, const u16* __restrict__ kcb,
    const float* __restrict__ w1, const float* __restrict__ b1,
    const float* __restrict__ w2, const float* __restrict__ b2,
    float* __restrict__ mout)
{
    __shared__ float ks[32][257];
    __shared__ float qs[8][257];
    int t = threadIdx.x;
    int l0 = blockIdx.x * 32, n0 = blockIdx.y * 8;
    for (int i = t; i < 32 * 256; i += 256)
        ks[i >> 8][i & 255] = bf2f(kcb[(size_t)(l0 + (i >> 8)) * CC + (i & 255)]);
    for (int i = t; i < 8 * 256; i += 256)
        qs[i >> 8][i & 255] = qc[(size_t)(n0 + (i >> 8)) * CC + (i & 255)];
    __syncthreads();
    int n = t >> 5, lx = t & 31;
    float s[8];
#pragma unroll
    for (int h = 0; h < 8; ++h) {
        float d = 0.f;
#pragma unroll
        for (int dd = 0; dd < 32; ++dd)
            d += qs[n][h * 32 + dd] * ks[lx][h * 32 + dd];
        s[h] = d * SCALE;
    }
    float acc2 = b2[0];
#pragma unroll
    for (int o = 0; o < 8; ++o) {
        float f = b1[o];
#pragma unroll
        for (int i = 0; i < 8; ++i) f += s[i] * w1[o * 8 + i];
        f = fmaxf(f, 0.f);
        acc2 += f * w2[o];
    }
    mout[(size_t)(n0 + n) * LL + l0 + lx] = fmaxf(acc2, 0.f);
}

// ---------------------------------------------------------------------------
// f32 LayerNorm over C=256 (r17-proven).
// ---------------------------------------------------------------------------
__global__ __launch_bounds__(256) void ln_f32(
    const float* __restrict__ a, const float* __restrict__ g,
    const float* __restrict__ be, float* __restrict__ out)
{
    int lane = threadIdx.x & 63, wave = threadIdx.x >> 6;
    int row = blockIdx.x * 4 + wave;
    float4 v = *(const float4*)(a + (size_t)row * CC + lane * 4);
    float sum = v.x + v.y + v.z + v.w;
    float sq = v.x * v.x + v.y * v.y + v.z * v.z + v.w * v.w;
#pragma unroll
    for (int mk = 1; mk < 64; mk <<= 1) {
        sum += __shfl_xor(sum, mk);
        sq += __shfl_xor(sq, mk);
    }
    float mean = sum * (1.f / 256.f);
    float var = sq * (1.f / 256.f) - mean * mean;
    float rstd = rsqrtf(var + 1e-5f);
    int c = lane * 4;
    float4 ov;
    ov.x = (v.x - mean) * rstd * g[c + 0] + be[c + 0];
    ov.y = (v.y - mean) * rstd * g[c + 1] + be[c + 1];
    ov.z = (v.z - mean) * rstd * g[c + 2] + be[c + 2];
    ov.w = (v.w - mean) * rstd * g[c + 3] + be[c + 3];
    *(float4*)(out + (size_t)row * CC + c) = ov;
}

// ---------------------------------------------------------------------------
extern "C" void kernel_launch(void* const* d_in, const int* in_sizes, int n_in,
                              void* d_out, int out_size, void* d_ws, size_t ws_size,
                              hipStream_t stream)
{
    (void)in_sizes; (void)n_in; (void)out_size;
    float* outx = (float*)d_out;
    float* outm = outx + (size_t)BB * NN * CC;

    const float* query     = (const float*)d_in[0];
    const float* key       = (const float*)d_in[1];
    const float* value     = (const float*)d_in[2];
    const float* sa_qkv_w  = (const float*)d_in[3];
    const float* sa_proj_w = (const float*)d_in[4];
    const float* sa_proj_b = (const float*)d_in[5];
    const float* norm3_g   = (const float*)d_in[6];
    const float* norm3_b   = (const float*)d_in[7];
    const float* q_w       = (const float*)d_in[8];
    const float* k_w       = (const float*)d_in[9];
    const float* v_w       = (const float*)d_in[10];
    const float* ca_proj_w = (const float*)d_in[11];
    const float* ca_proj_b = (const float*)d_in[12];
    const float* l1_w      = (const float*)d_in[13];
    const float* l1_b      = (const float*)d_in[14];
    const float* l2_w      = (const float*)d_in[15];
    const float* l2_b      = (const float*)d_in[16];
    const float* ln1_g     = (const float*)d_in[17];
    const float* ln1_b     = (const float*)d_in[18];
    const float* ln2_g     = (const float*)d_in[19];
    const float* ln2_b     = (const float*)d_in[20];
    const float* fc1_w     = (const float*)d_in[21];
    const float* fc1_b     = (const float*)d_in[22];
    const float* fc2_w     = (const float*)d_in[23];
    const float* fc2_b     = (const float*)d_in[24];

    const int NSPLIT = 8;

    char* w0 = (char*)d_ws;
    char* unionA = w0;                 w0 += (size_t)16 * 1024 * 1024;
    float* saH = (float*)w0;           w0 += (size_t)1024 * 256 * 4;
    float* x1  = (float*)w0;           w0 += (size_t)1024 * 256 * 4;
    float* x2  = (float*)w0;           w0 += (size_t)1024 * 256 * 4;
    float* tmp = (float*)w0;           w0 += (size_t)1024 * 256 * 4;
    float* qc  = (float*)w0;           w0 += (size_t)1024 * 256 * 4;
    float* caH = (float*)w0;           w0 += (size_t)1024 * 256 * 4;
    u16*   qc_b = (u16*)w0;            w0 += (size_t)1024 * 256 * 2;
    float* po  = (float*)w0;           w0 += (size_t)NSPLIT * 512 * 256 * 4;  // 4 MB
    float* pm  = (float*)w0;           w0 += (size_t)NSPLIT * 512 * 8 * 4;
    float* ps  = (float*)w0;           w0 += (size_t)NSPLIT * 512 * 8 * 4;
    size_t need = (size_t)(w0 - (char*)d_ws);
    // unionA phase 1: qkv_b (1.5MB) + vst (0.5MB); phase 2 (per b): kc_b/vc_b/vt_b (12MB); phase 3: hb (4MB)
    u16* qkv_b = (u16*)unionA;                                   // 1024 x 768
    u16* vst   = (u16*)(unionA + (size_t)1024 * 768 * 2);        // (B,H,D,512)
    u16* kc_b  = (u16*)unionA;                                   // 8192 x 256
    u16* vc_b  = (u16*)(unionA + (size_t)8192 * 256 * 2);        // 8192 x 256
    u16* vt_b  = (u16*)(unionA + (size_t)2 * 8192 * 256 * 2);    // (H,D,8192)
    float* hb  = (float*)unionA;                                 // 1024 x 1024

    if (ws_size < need) {
        sentinel<<<dim3(1), dim3(64), 0, stream>>>(outx, 1000.f + (float)(ws_size >> 20));
        return;
    }

    dim3 blk(256);

    // 1. qkv (bf16) = query @ sa_qkv_w.T
    sgemm_t<0, 0, false, 1><<<dim3(16, 12), blk, 0, stream>>>(query, sa_qkv_w, nullptr, nullptr, nullptr, qkv_b, 1024, 768, 256);
    // 2. self V^T (B,H,D,N) from qkv_b cols 512:768
    transpose_bf<<<dim3(8, 8, 2), blk, 0, stream>>>(qkv_b + 512, vst, 768, 512, (size_t)512 * 768, (size_t)8 * 32 * 512);
    // 3. self attention (MFMA) -> saH
    attn_mfma<false><<<dim3(16, 8, 2), blk, 0, stream>>>(qkv_b, qkv_b + 256, vst, saH, nullptr, nullptr, 512, 768, 768, 512, 512);
    // 4. sa proj + bias + residual(query) -> tmp
    sgemm_t<1, 0, true, 0><<<dim3(16, 4), blk, 0, stream>>>(saH, sa_proj_w, sa_proj_b, query, tmp, nullptr, 1024, 256, 256);
    // 5. LN(norm3) -> x1
    ln_f32<<<dim3(256), blk, 0, stream>>>(tmp, norm3_g, norm3_b, x1);
    // 6. qc (f32 + bf16) = x1 @ q_w.T
    sgemm_t<0, 0, false, 2><<<dim3(16, 4), blk, 0, stream>>>(x1, q_w, nullptr, nullptr, qc, qc_b, 1024, 256, 256);
    // 7-10. per-batch: kc_b, vc_b, V^T, cross attn (split x8 + combine), mask
    for (int b = 0; b < 2; ++b) {
        const float* keyb = key + (size_t)b * 8192 * 256;
        const float* valb = value + (size_t)b * 8192 * 256;
        sgemm_t<0, 0, false, 1><<<dim3(128, 4), blk, 0, stream>>>(keyb, k_w, nullptr, nullptr, nullptr, kc_b, 8192, 256, 256);
        sgemm_t<0, 0, false, 1><<<dim3(128, 4), blk, 0, stream>>>(valb, v_w, nullptr, nullptr, nullptr, vc_b, 8192, 256, 256);
        transpose_bf<<<dim3(128, 8, 1), blk, 0, stream>>>(vc_b, vt_b, 256, 8192, 0, 0);
        attn_mfma<true><<<dim3(16, 8, NSPLIT), blk, 0, stream>>>(qc_b + (size_t)b * 512 * 256, kc_b, vt_b, po, pm, ps, 8192, 256, 256, 8192, 512);
        attn_combine<<<dim3(512), blk, 0, stream>>>(po, pm, ps, caH + (size_t)b * 512 * 256, 512, NSPLIT);
        smask2<<<dim3(256, 64), blk, 0, stream>>>(qc + (size_t)b * 512 * 256, kc_b, l1_w, l1_b, l2_w, l2_b,
                                                  outm + (size_t)b * 512 * 8192);
    }
    // 11. ca proj + bias + residual(x1) -> tmp
    sgemm_t<1, 0, true, 0><<<dim3(16, 4), blk, 0, stream>>>(caH, ca_proj_w, ca_proj_b, x1, tmp, nullptr, 1024, 256, 256);
    // 12. LN(ln1) -> x2
    ln_f32<<<dim3(256), blk, 0, stream>>>(tmp, ln1_g, ln1_b, x2);
    // 13. fc1 + bias + GELU -> hb
    sgemm_t<0, 1, true, 0><<<dim3(16, 16), blk, 0, stream>>>(x2, fc1_w, fc1_b, nullptr, hb, nullptr, 1024, 1024, 256);
    // 14. fc2 + bias + residual(x2) -> tmp
    sgemm_t<1, 0, true, 0><<<dim3(16, 4), blk, 0, stream>>>(hb, fc2_w, fc2_b, x2, tmp, nullptr, 1024, 256, 1024);
    // 15. LN(ln2) -> outx
    ln_f32<<<dim3(256), blk, 0, stream>>>(tmp, ln2_g, ln2_b, outx);
}

// Round 21
// 311.283 us; speedup vs baseline: 24.7674x; 1.8780x over previous
//
#include <hip/hip_runtime.h>
#include <hip/hip_bf16.h>

#define BB 2
#define NN 512
#define LL 8192
#define CC 256
#define HH 8
#define DD 32
#define SCALE 0.17677669529663687f

typedef unsigned short u16;
typedef unsigned int u32;
typedef __attribute__((ext_vector_type(8))) short bf16x8;
typedef __attribute__((ext_vector_type(4))) float f32x4;

__device__ __forceinline__ float bf2f(u16 v) { return __uint_as_float(((u32)v) << 16); }
__device__ __forceinline__ u16 f2bf(float f) {
    u32 u = __float_as_uint(f);
    return (u16)((u + 0x7fffu + ((u >> 16) & 1u)) >> 16);
}
__device__ __forceinline__ bf16x8 ld8(const u16* p) { return *(const bf16x8*)p; }

__global__ void sentinel(float* out, float val) {
    if (threadIdx.x == 0) out[0] = val;
}

// ---------------------------------------------------------------------------
// Tiled f32 GEMM, optional bf16 output copy. OUT: 0 f32, 1 bf16, 2 both.
// ---------------------------------------------------------------------------
template <int RES, int ACT, bool HAS_BIAS, int OUT>
__global__ __launch_bounds__(256) void sgemm_t(
    const float* __restrict__ A, const float* __restrict__ W,
    const float* __restrict__ bias, const float* __restrict__ res,
    float* __restrict__ Cf, u16* __restrict__ Cb, int M, int N, int K)
{
    __shared__ float As[32][68], Ws[32][68];
    int t = threadIdx.x;
    int ty = t >> 4, tx = t & 15;
    int m0 = blockIdx.x * 64, n0 = blockIdx.y * 64;
    float acc[4][4] = {};
    for (int k0 = 0; k0 < K; k0 += 32) {
#pragma unroll
        for (int j = 0; j < 2; ++j) {
            int idx = t + j * 256;
            int row = idx >> 3, c4 = idx & 7;
            float4 av = *(const float4*)&A[(size_t)(m0 + row) * K + k0 + c4 * 4];
            As[c4 * 4 + 0][row] = av.x; As[c4 * 4 + 1][row] = av.y;
            As[c4 * 4 + 2][row] = av.z; As[c4 * 4 + 3][row] = av.w;
            float4 wv = *(const float4*)&W[(size_t)(n0 + row) * K + k0 + c4 * 4];
            Ws[c4 * 4 + 0][row] = wv.x; Ws[c4 * 4 + 1][row] = wv.y;
            Ws[c4 * 4 + 2][row] = wv.z; Ws[c4 * 4 + 3][row] = wv.w;
        }
        __syncthreads();
#pragma unroll
        for (int kk = 0; kk < 32; ++kk) {
            float4 av = *(const float4*)&As[kk][ty * 4];
            float4 wv = *(const float4*)&Ws[kk][tx * 4];
            float a_[4] = {av.x, av.y, av.z, av.w};
            float w_[4] = {wv.x, wv.y, wv.z, wv.w};
#pragma unroll
            for (int r = 0; r < 4; ++r)
#pragma unroll
                for (int c = 0; c < 4; ++c)
                    acc[r][c] += a_[r] * w_[c];
        }
        __syncthreads();
    }
#pragma unroll
    for (int r = 0; r < 4; ++r) {
        int row = m0 + ty * 4 + r;
#pragma unroll
        for (int c = 0; c < 4; ++c) {
            int col = n0 + tx * 4 + c;
            float v = acc[r][c];
            if (HAS_BIAS) v += bias[col];
            if (RES) v += res[(size_t)row * N + col];
            if (ACT) v = 0.5f * v * (1.f + erff(v * 0.70710678118f));
            if (OUT == 0 || OUT == 2) Cf[(size_t)row * N + col] = v;
            if (OUT == 1 || OUT == 2) Cb[(size_t)row * N + col] = f2bf(v);
        }
    }
}

// ---------------------------------------------------------------------------
// bf16 head-transpose (r20 proven).
// ---------------------------------------------------------------------------
__global__ __launch_bounds__(256) void transpose_bf(
    const u16* __restrict__ in, u16* __restrict__ out,
    int rowStride, int vtL, size_t bStrideIn, size_t bStrideOut)
{
    __shared__ alignas(16) u16 tl[64][33];
    int r0 = blockIdx.x * 64;
    int h = blockIdx.y, b = blockIdx.z;
    const u16* ip = in + (size_t)b * bStrideIn + h * DD;
    for (int i = threadIdx.x; i < 64 * 32; i += 256) {
        int r = i >> 5, d = i & 31;
        tl[r][d] = ip[(size_t)(r0 + r) * rowStride + d];
    }
    __syncthreads();
    u16* op = out + (size_t)b * bStrideOut + (size_t)h * DD * vtL + r0;
    for (int i = threadIdx.x; i < 64 * 32; i += 256) {
        int r = i & 63, d = i >> 6;
        op[(size_t)d * vtL + r] = tl[r][d];
    }
}

// ---------------------------------------------------------------------------
// MFMA flash attention (r20 proven).
// ---------------------------------------------------------------------------
template <bool SPLIT>
__global__ __launch_bounds__(256) void attn_mfma(
    const u16* __restrict__ qp, const u16* __restrict__ kp,
    const u16* __restrict__ vt, float* __restrict__ outp,
    float* __restrict__ pm, float* __restrict__ ps_,
    int Lk, int qStride, int kStride, int vtL, int Nq)
{
    __shared__ alignas(16) u16 plds[4][32][48];
    __shared__ alignas(16) float comb[4][32][34];
    int lane = threadIdx.x & 63, wave = threadIdx.x >> 6;
    int lr = lane & 15, lg = lane >> 4;
    int h = blockIdx.y, n0 = blockIdx.x * 32, z = blockIdx.z;
    size_t qoff = 0, koff = 0, voff = 0;
    int lbeg, lend;
    if (SPLIT) {
        int chunk = Lk / (gridDim.z * 4);
        lbeg = z * (Lk / gridDim.z) + wave * chunk;
        lend = lbeg + chunk;
    } else {
        int chunk = Lk / 4;
        lbeg = wave * chunk;
        lend = lbeg + chunk;
        qoff = (size_t)z * Nq * qStride;
        koff = (size_t)z * Lk * kStride;
        voff = (size_t)z * HH * DD * vtL;
    }

    bf16x8 bq[2];
#pragma unroll
    for (int nh = 0; nh < 2; ++nh)
        bq[nh] = ld8(qp + qoff + (size_t)(n0 + nh * 16 + lr) * qStride + h * DD + lg * 8);

    f32x4 o[2][2] = {};
    float m = -1e30f, s = 0.f;
    float m2 = -1e30f, s2 = 0.f;
    const u16* kb = kp + koff + h * DD + lg * 8;
    const u16* vb0 = vt + voff + (size_t)h * DD * vtL;

    for (int l0 = lbeg; l0 < lend; l0 += 32) {
        bf16x8 ka[2];
#pragma unroll
        for (int lt = 0; lt < 2; ++lt)
            ka[lt] = ld8(kb + (size_t)(l0 + lt * 16 + lr) * kStride);
        f32x4 st[2][2];
#pragma unroll
        for (int lt = 0; lt < 2; ++lt)
#pragma unroll
            for (int nh = 0; nh < 2; ++nh) {
                f32x4 zz = {0.f, 0.f, 0.f, 0.f};
                st[lt][nh] = __builtin_amdgcn_mfma_f32_16x16x32_bf16(ka[lt], bq[nh], zz, 0, 0, 0);
            }
        float aq[2];
#pragma unroll
        for (int nh = 0; nh < 2; ++nh) {
            float mprev = (nh == 0) ? m : m2;
            float sprev = (nh == 0) ? s : s2;
            float mx = -1e30f;
#pragma unroll
            for (int lt = 0; lt < 2; ++lt)
#pragma unroll
                for (int r = 0; r < 4; ++r) {
                    float v = st[lt][nh][r] * SCALE;
                    st[lt][nh][r] = v;
                    mx = fmaxf(mx, v);
                }
            mx = fmaxf(mx, __shfl_xor(mx, 16));
            mx = fmaxf(mx, __shfl_xor(mx, 32));
            float mn = fmaxf(mprev, mx);
            float alpha = __expf(mprev - mn);
            float rs = 0.f;
#pragma unroll
            for (int lt = 0; lt < 2; ++lt) {
                u16 pk[4];
#pragma unroll
                for (int r = 0; r < 4; ++r) {
                    float p = __expf(st[lt][nh][r] - mn);
                    rs += p;
                    pk[r] = f2bf(p);
                }
                uint2 pv;
                pv.x = (u32)pk[0] | ((u32)pk[1] << 16);
                pv.y = (u32)pk[2] | ((u32)pk[3] << 16);
                *(uint2*)&plds[wave][nh * 16 + lr][lt * 16 + lg * 4] = pv;
            }
            rs += __shfl_xor(rs, 16);
            rs += __shfl_xor(rs, 32);
            if (nh == 0) { s = sprev * alpha + rs; m = mn; }
            else         { s2 = sprev * alpha + rs; m2 = mn; }
            aq[nh] = alpha;
        }
#pragma unroll
        for (int qt = 0; qt < 2; ++qt)
#pragma unroll
            for (int r = 0; r < 4; ++r) {
                float al = __shfl(aq[qt], (lg << 2) + r);
                o[qt][0][r] *= al;
                o[qt][1][r] *= al;
            }
        asm volatile("" ::: "memory");
        bf16x8 pa[2], vv[2];
#pragma unroll
        for (int qt = 0; qt < 2; ++qt)
            pa[qt] = ld8(&plds[wave][qt * 16 + lr][lg * 8]);
        asm volatile("" ::: "memory");
#pragma unroll
        for (int dt = 0; dt < 2; ++dt)
            vv[dt] = ld8(vb0 + (size_t)(dt * 16 + lr) * vtL + l0 + lg * 8);
#pragma unroll
        for (int qt = 0; qt < 2; ++qt)
#pragma unroll
            for (int dt = 0; dt < 2; ++dt)
                o[qt][dt] = __builtin_amdgcn_mfma_f32_16x16x32_bf16(pa[qt], vv[dt], o[qt][dt], 0, 0, 0);
    }

#pragma unroll
    for (int qt = 0; qt < 2; ++qt)
#pragma unroll
        for (int dt = 0; dt < 2; ++dt)
#pragma unroll
            for (int r = 0; r < 4; ++r)
                comb[wave][qt * 16 + lg * 4 + r][dt * 16 + lr] = o[qt][dt][r];
    if (lg == 0) {
        comb[wave][lr][32] = m;       comb[wave][lr][33] = s;
        comb[wave][16 + lr][32] = m2; comb[wave][16 + lr][33] = s2;
    }
    __syncthreads();
    for (int idx = threadIdx.x; idx < 1024; idx += 256) {
        int q2 = idx >> 5, d = idx & 31;
        float mm = -1e30f;
#pragma unroll
        for (int w = 0; w < 4; ++w) mm = fmaxf(mm, comb[w][q2][32]);
        float num = 0.f, den = 0.f;
#pragma unroll
        for (int w = 0; w < 4; ++w) {
            float e = __expf(comb[w][q2][32] - mm);
            num += e * comb[w][q2][d];
            den += e * comb[w][q2][33];
        }
        int n = n0 + q2;
        if (SPLIT) {
            outp[((size_t)z * Nq + n) * CC + h * DD + d] = num;
            if (d == 0) {
                pm[((size_t)z * Nq + n) * HH + h] = mm;
                ps_[((size_t)z * Nq + n) * HH + h] = den;
            }
        } else {
            outp[((size_t)z * Nq + n) * CC + h * DD + d] = num / den;
        }
    }
}

// ---------------------------------------------------------------------------
// Combine flash partials (r19/r20 proven).
// ---------------------------------------------------------------------------
__global__ __launch_bounds__(256) void attn_combine(
    const float* __restrict__ po, const float* __restrict__ pm,
    const float* __restrict__ ps, float* __restrict__ out,
    int Nq, int nsplit)
{
    int idx = blockIdx.x * 256 + threadIdx.x;
    if (idx >= Nq * CC) return;
    int n = idx >> 8, cd = idx & 255;
    int h = cd >> 5;
    float mm = -1e30f;
    for (int zz = 0; zz < nsplit; ++zz)
        mm = fmaxf(mm, pm[((size_t)zz * Nq + n) * HH + h]);
    float num = 0.f, den = 0.f;
    for (int zz = 0; zz < nsplit; ++zz) {
        float e = __expf(pm[((size_t)zz * Nq + n) * HH + h] - mm);
        num += e * po[((size_t)zz * Nq + n) * CC + cd];
        den += e * ps[((size_t)zz * Nq + n) * HH + h];
    }
    out[(size_t)n * CC + cd] = num / den;
}

// ---------------------------------------------------------------------------
// MFMA mask: per wave, 16-l tile x 32 n (2 n-tiles), 8 head-MFMAs put all 8
// head scores of a given (n,l) in the same lane/reg slot (n=lane&15,
// l=(lane>>4)*4+r). The 8->8->1 MLP is lane-local; weights wave-uniform
// (SGPR). No LDS. Coalesced float4 stores (r spans 4 consecutive l).
// Grid (L/(64*NL), N/32, B); each block does NL l-tiles of 64 (wave = 16 l).
// ---------------------------------------------------------------------------
template <int NL>
__global__ __launch_bounds__(256) void smask_mfma(
    const u16* __restrict__ qcb, const u16* __restrict__ kcb,
    const float* __restrict__ w1, const float* __restrict__ b1,
    const float* __restrict__ w2, const float* __restrict__ b2,
    float* __restrict__ mout)
{
    int lane = threadIdx.x & 63, wave = threadIdx.x >> 6;
    int lr = lane & 15, lg = lane >> 4;
    int n0 = blockIdx.y * 32;
    bf16x8 bq[8][2];
#pragma unroll
    for (int h = 0; h < 8; ++h)
#pragma unroll
        for (int nh = 0; nh < 2; ++nh)
            bq[h][nh] = ld8(qcb + (size_t)(n0 + nh * 16 + lr) * CC + h * DD + lg * 8);
    float b2v = b2[0];
    for (int it = 0; it < NL; ++it) {
        int l0 = (blockIdx.x * NL + it) * 64 + wave * 16;
        bf16x8 ka[8];
#pragma unroll
        for (int h = 0; h < 8; ++h)
            ka[h] = ld8(kcb + (size_t)(l0 + lr) * CC + h * DD + lg * 8);
#pragma unroll
        for (int nh = 0; nh < 2; ++nh) {
            f32x4 st[8];
#pragma unroll
            for (int h = 0; h < 8; ++h) {
                f32x4 zz = {0.f, 0.f, 0.f, 0.f};
                st[h] = __builtin_amdgcn_mfma_f32_16x16x32_bf16(ka[h], bq[h][nh], zz, 0, 0, 0);
            }
            float4 res;
            float* rp = &res.x;
#pragma unroll
            for (int r = 0; r < 4; ++r) {
                float s[8];
#pragma unroll
                for (int i = 0; i < 8; ++i) s[i] = st[i][r] * SCALE;
                float acc2 = b2v;
#pragma unroll
                for (int o = 0; o < 8; ++o) {
                    float f = b1[o];
#pragma unroll
                    for (int i = 0; i < 8; ++i) f += s[i] * w1[o * 8 + i];
                    f = fmaxf(f, 0.f);
                    acc2 += f * w2[o];
                }
                rp[r] = fmaxf(acc2, 0.f);
            }
            *(float4*)&mout[(size_t)(n0 + nh * 16 + lr) * LL + l0 + lg * 4] = res;
        }
    }
}

// ---------------------------------------------------------------------------
// f32 LayerNorm over C=256 (r17 proven).
// ---------------------------------------------------------------------------
__global__ __launch_bounds__(256) void ln_f32(
    const float* __restrict__ a, const float* __restrict__ g,
    const float* __restrict__ be, float* __restrict__ out)
{
    int lane = threadIdx.x & 63, wave = threadIdx.x >> 6;
    int row = blockIdx.x * 4 + wave;
    float4 v = *(const float4*)(a + (size_t)row * CC + lane * 4);
    float sum = v.x + v.y + v.z + v.w;
    float sq = v.x * v.x + v.y * v.y + v.z * v.z + v.w * v.w;
#pragma unroll
    for (int mk = 1; mk < 64; mk <<= 1) {
        sum += __shfl_xor(sum, mk);
        sq += __shfl_xor(sq, mk);
    }
    float mean = sum * (1.f / 256.f);
    float var = sq * (1.f / 256.f) - mean * mean;
    float rstd = rsqrtf(var + 1e-5f);
    int c = lane * 4;
    float4 ov;
    ov.x = (v.x - mean) * rstd * g[c + 0] + be[c + 0];
    ov.y = (v.y - mean) * rstd * g[c + 1] + be[c + 1];
    ov.z = (v.z - mean) * rstd * g[c + 2] + be[c + 2];
    ov.w = (v.w - mean) * rstd * g[c + 3] + be[c + 3];
    *(float4*)(out + (size_t)row * CC + c) = ov;
}

// ---------------------------------------------------------------------------
extern "C" void kernel_launch(void* const* d_in, const int* in_sizes, int n_in,
                              void* d_out, int out_size, void* d_ws, size_t ws_size,
                              hipStream_t stream)
{
    (void)in_sizes; (void)n_in; (void)out_size;
    float* outx = (float*)d_out;
    float* outm = outx + (size_t)BB * NN * CC;

    const float* query     = (const float*)d_in[0];
    const float* key       = (const float*)d_in[1];
    const float* value     = (const float*)d_in[2];
    const float* sa_qkv_w  = (const float*)d_in[3];
    const float* sa_proj_w = (const float*)d_in[4];
    const float* sa_proj_b = (const float*)d_in[5];
    const float* norm3_g   = (const float*)d_in[6];
    const float* norm3_b   = (const float*)d_in[7];
    const float* q_w       = (const float*)d_in[8];
    const float* k_w       = (const float*)d_in[9];
    const float* v_w       = (const float*)d_in[10];
    const float* ca_proj_w = (const float*)d_in[11];
    const float* ca_proj_b = (const float*)d_in[12];
    const float* l1_w      = (const float*)d_in[13];
    const float* l1_b      = (const float*)d_in[14];
    const float* l2_w      = (const float*)d_in[15];
    const float* l2_b      = (const float*)d_in[16];
    const float* ln1_g     = (const float*)d_in[17];
    const float* ln1_b     = (const float*)d_in[18];
    const float* ln2_g     = (const float*)d_in[19];
    const float* ln2_b     = (const float*)d_in[20];
    const float* fc1_w     = (const float*)d_in[21];
    const float* fc1_b     = (const float*)d_in[22];
    const float* fc2_w     = (const float*)d_in[23];
    const float* fc2_b     = (const float*)d_in[24];

    const int NSPLIT = 8;

    char* w0 = (char*)d_ws;
    char* unionA = w0;                 w0 += (size_t)16 * 1024 * 1024;
    float* saH = (float*)w0;           w0 += (size_t)1024 * 256 * 4;
    float* x1  = (float*)w0;           w0 += (size_t)1024 * 256 * 4;
    float* x2  = (float*)w0;           w0 += (size_t)1024 * 256 * 4;
    float* tmp = (float*)w0;           w0 += (size_t)1024 * 256 * 4;
    float* caH = (float*)w0;           w0 += (size_t)1024 * 256 * 4;
    u16*   qc_b = (u16*)w0;            w0 += (size_t)1024 * 256 * 2;
    float* po  = (float*)w0;           w0 += (size_t)NSPLIT * 512 * 256 * 4;
    float* pm  = (float*)w0;           w0 += (size_t)NSPLIT * 512 * 8 * 4;
    float* ps  = (float*)w0;           w0 += (size_t)NSPLIT * 512 * 8 * 4;
    size_t need = (size_t)(w0 - (char*)d_ws);
    u16* qkv_b = (u16*)unionA;                                   // 1024 x 768
    u16* vst   = (u16*)(unionA + (size_t)1024 * 768 * 2);        // (B,H,D,512)
    u16* kc_b  = (u16*)unionA;                                   // 8192 x 256
    u16* vc_b  = (u16*)(unionA + (size_t)8192 * 256 * 2);        // 8192 x 256
    u16* vt_b  = (u16*)(unionA + (size_t)2 * 8192 * 256 * 2);    // (H,D,8192)
    float* hb  = (float*)unionA;                                 // 1024 x 1024

    if (ws_size < need) {
        sentinel<<<dim3(1), dim3(64), 0, stream>>>(outx, 1000.f + (float)(ws_size >> 20));
        return;
    }

    dim3 blk(256);

    // 1. qkv (bf16) = query @ sa_qkv_w.T
    sgemm_t<0, 0, false, 1><<<dim3(16, 12), blk, 0, stream>>>(query, sa_qkv_w, nullptr, nullptr, nullptr, qkv_b, 1024, 768, 256);
    // 2. self V^T
    transpose_bf<<<dim3(8, 8, 2), blk, 0, stream>>>(qkv_b + 512, vst, 768, 512, (size_t)512 * 768, (size_t)8 * 32 * 512);
    // 3. self attention (MFMA) -> saH
    attn_mfma<false><<<dim3(16, 8, 2), blk, 0, stream>>>(qkv_b, qkv_b + 256, vst, saH, nullptr, nullptr, 512, 768, 768, 512, 512);
    // 4. sa proj + bias + residual(query) -> tmp
    sgemm_t<1, 0, true, 0><<<dim3(16, 4), blk, 0, stream>>>(saH, sa_proj_w, sa_proj_b, query, tmp, nullptr, 1024, 256, 256);
    // 5. LN(norm3) -> x1
    ln_f32<<<dim3(256), blk, 0, stream>>>(tmp, norm3_g, norm3_b, x1);
    // 6. qc (bf16) = x1 @ q_w.T
    sgemm_t<0, 0, false, 1><<<dim3(16, 4), blk, 0, stream>>>(x1, q_w, nullptr, nullptr, nullptr, qc_b, 1024, 256, 256);
    // 7-10. per-batch
    for (int b = 0; b < 2; ++b) {
        const float* keyb = key + (size_t)b * 8192 * 256;
        const float* valb = value + (size_t)b * 8192 * 256;
        const u16* qcb = qc_b + (size_t)b * 512 * 256;
        sgemm_t<0, 0, false, 1><<<dim3(128, 4), blk, 0, stream>>>(keyb, k_w, nullptr, nullptr, nullptr, kc_b, 8192, 256, 256);
        sgemm_t<0, 0, false, 1><<<dim3(128, 4), blk, 0, stream>>>(valb, v_w, nullptr, nullptr, nullptr, vc_b, 8192, 256, 256);
        transpose_bf<<<dim3(128, 8, 1), blk, 0, stream>>>(vc_b, vt_b, 256, 8192, 0, 0);
        attn_mfma<true><<<dim3(16, 8, NSPLIT), blk, 0, stream>>>(qcb, kc_b, vt_b, po, pm, ps, 8192, 256, 256, 8192, 512);
        attn_combine<<<dim3(512), blk, 0, stream>>>(po, pm, ps, caH + (size_t)b * 512 * 256, 512, NSPLIT);
        smask_mfma<4><<<dim3(32, 16), blk, 0, stream>>>(qcb, kc_b, l1_w, l1_b, l2_w, l2_b,
                                                        outm + (size_t)b * 512 * 8192);
    }
    // 11. ca proj + bias + residual(x1) -> tmp
    sgemm_t<1, 0, true, 0><<<dim3(16, 4), blk, 0, stream>>>(caH, ca_proj_w, ca_proj_b, x1, tmp, nullptr, 1024, 256, 256);
    // 12. LN(ln1) -> x2
    ln_f32<<<dim3(256), blk, 0, stream>>>(tmp, ln1_g, ln1_b, x2);
    // 13. fc1 + bias + GELU -> hb
    sgemm_t<0, 1, true, 0><<<dim3(16, 16), blk, 0, stream>>>(x2, fc1_w, fc1_b, nullptr, hb, nullptr, 1024, 1024, 256);
    // 14. fc2 + bias + residual(x2) -> tmp
    sgemm_t<1, 0, true, 0><<<dim3(16, 4), blk, 0, stream>>>(hb, fc2_w, fc2_b, x2, tmp, nullptr, 1024, 256, 1024);
    // 15. LN(ln2) -> outx
    ln_f32<<<dim3(256), blk, 0, stream>>>(tmp, ln2_g, ln2_b, outx);
}